// Round 3
// baseline (361.156 us; speedup 1.0000x reference)
//
#include <hip/hip_runtime.h>

#define NN 163842
#define NE 983040
#define NB 641   // ceil(NN/256)

using short8   = __attribute__((ext_vector_type(8))) short;
using ushort8v = __attribute__((ext_vector_type(8))) unsigned short;
using f32x4    = __attribute__((ext_vector_type(4))) float;

// ---------------- degree count (int) ----------------
__global__ __launch_bounds__(256) void deg_count(const int* __restrict__ dst,
                                                 int* __restrict__ degi, int E) {
    int e = blockIdx.x * 256 + threadIdx.x;
    if (e < E) atomicAdd(&degi[dst[e]], 1);
}

// ---------------- exclusive scan of degi -> cursor ----------------
__global__ __launch_bounds__(256) void scan1(const int* __restrict__ degi,
                                             int* __restrict__ cursor,
                                             int* __restrict__ bsum, int n) {
    __shared__ int tmp[256];
    int t = threadIdx.x;
    int i = blockIdx.x * 256 + t;
    int v = (i < n) ? degi[i] : 0;
    tmp[t] = v;
    __syncthreads();
    for (int o = 1; o < 256; o <<= 1) {
        int x = (t >= o) ? tmp[t - o] : 0;
        __syncthreads();
        tmp[t] += x;
        __syncthreads();
    }
    if (i < n) cursor[i] = tmp[t] - v;            // exclusive
    if (t == 255) bsum[blockIdx.x] = tmp[255];    // block total
}

__global__ void scan2(int* __restrict__ bsum, int nb) {
    __shared__ int tmp[1024];
    int t = threadIdx.x;
    int v = (t < nb) ? bsum[t] : 0;
    tmp[t] = v;
    __syncthreads();
    for (int o = 1; o < 1024; o <<= 1) {
        int x = (t >= o) ? tmp[t - o] : 0;
        __syncthreads();
        tmp[t] += x;
        __syncthreads();
    }
    if (t < nb) bsum[t] = tmp[t] - v;
}

__global__ __launch_bounds__(256) void scan3(int* __restrict__ cursor,
                                             const int* __restrict__ bsum, int n) {
    int i = blockIdx.x * 256 + threadIdx.x;
    if (i < n) cursor[i] += bsum[blockIdx.x];
}

static __device__ __forceinline__ unsigned short bf16rne(float x) {
    unsigned u = __float_as_uint(x);
    u += 0x7FFFu + ((u >> 16) & 1u);      // round-to-nearest-even
    return (unsigned short)(u >> 16);
}

static __device__ __forceinline__ float bf2f(unsigned short u) {
    return __uint_as_float(((unsigned)u) << 16);
}

// ---- CSR position scatter: ONLY a 4-B edge index goes to a random address ----
// Round-2 lesson: 16-B random writes of gedr hit 4.6x cross-XCD line amplification
// (WRITE_SIZE 73 MB for a 15.7 MB array). 4-B payload cuts the randomly-dirtied
// footprint to 3.9 MB (~16 MB HBM after amplification). 2 edges/thread = 2
// independent atomic chains in flight per lane.
__global__ __launch_bounds__(256) void scatter_idx(const int* __restrict__ dst,
                                                   int* __restrict__ cursor,
                                                   int* __restrict__ eidx, int E) {
    int e0 = blockIdx.x * 512 + threadIdx.x;
    int e1 = e0 + 256;
    int d0 = (e0 < E) ? dst[e0] : 0;
    int d1 = (e1 < E) ? dst[e1] : 0;
    int p0 = 0, p1 = 0;
    if (e0 < E) p0 = atomicAdd(&cursor[d0], 1);
    if (e1 < E) p1 = atomicAdd(&cursor[d1], 1);
    if (e0 < E) eidx[p0] = e0;
    if (e1 < E) eidx[p1] = e1;
}

// ---- transposed bf16 weights Wcb[n][k], k-major ----
template <int CIN, int CINP, int COUTR>
static __device__ __forceinline__ void wcb_emit(int t, const float* __restrict__ g,
                                                const float* __restrict__ root,
                                                unsigned short* __restrict__ Wcb) {
    constexpr int KTl = 4 * CINP;
    int nIdx = t / KTl, k = t - nIdx * KTl;
    int seg = k / CINP, c = k - seg * CINP;
    float v = 0.0f;
    if (c < CIN)
        v = (seg < 3) ? g[c * (3 * COUTR) + seg * COUTR + nIdx] : root[c * COUTR + nIdx];
    Wcb[t] = bf16rne(v);
}

// ---- ONE launch: CSR-ordered record build (streaming write, random READS) +
//      x->bf16 pad + all 3 Wcb builds, as disjoint block ranges ----
// Records: p streams, e=eidx[p] (coalesced), src[e] 4 B + ea[e] 8 B random gathers
// (independent loads, full MLP, L2/L3-resident 11 MB) -> gedr[p] coalesced 16-B store.
__global__ __launch_bounds__(256) void gather_build(const int* __restrict__ eidx,
                                                    const int* __restrict__ src,
                                                    const float* __restrict__ ea,
                                                    float4* __restrict__ gedr,
                                                    const float* __restrict__ x,
                                                    unsigned short* __restrict__ xp,
                                                    const float* __restrict__ g0, const float* __restrict__ rt0,
                                                    const float* __restrict__ g1, const float* __restrict__ rt1,
                                                    const float* __restrict__ g2, const float* __restrict__ rt2,
                                                    unsigned short* __restrict__ W0,
                                                    unsigned short* __restrict__ W1,
                                                    unsigned short* __restrict__ W2,
                                                    int E, int EBLK, int PBLK, int n) {
    int bid = blockIdx.x;
    if (bid < EBLK) {
        int p = bid * 256 + threadIdx.x;
        if (p >= E) return;
        int e = eidx[p];
        float2 exy = *(const float2*)(ea + 2 * (size_t)e);
        gedr[p] = make_float4(__int_as_float(src[e]), exy.x, exy.y, 0.0f);
        return;
    }
    bid -= EBLK;
    if (bid < PBLK) {
        // ---- pad path: one thread per node, float2 loads + ushort8 stores ----
        int r = bid * 256 + threadIdx.x;
        if (r >= n) return;
        float v[22];
        const float2* x2 = (const float2*)(x + (size_t)r * 22);  // 88 B row, 8-aligned
#pragma unroll
        for (int j = 0; j < 11; ++j) *(float2*)(v + 2 * j) = x2[j];
        unsigned short* op = xp + (size_t)r * 32;
#pragma unroll
        for (int g8 = 0; g8 < 4; ++g8) {
            ushort8v o;
#pragma unroll
            for (int j = 0; j < 8; ++j) {
                int c = g8 * 8 + j;
                o[j] = (c < 22) ? bf16rne(v[c]) : (unsigned short)0;
            }
            *(ushort8v*)(op + g8 * 8) = o;
        }
        return;
    }
    bid -= PBLK;
    int t = bid * 256 + threadIdx.x;
    constexpr int T0 = 32 * 128, T1 = 64 * 128, T2 = 64 * 256;
    if (t < T0)                wcb_emit<22, 32, 32>(t, g0, rt0, W0);
    else if (t < T0 + T1)      wcb_emit<32, 32, 64>(t - T0, g1, rt1, W1);
    else if (t < T0 + T1 + T2) wcb_emit<64, 64, 64>(t - T0 - T1, g2, rt2, W2);
}

static __device__ __forceinline__ void fma4(float4& a, float g, const float4& hv) {
    a.x = fmaf(g, hv.x, a.x);
    a.y = fmaf(g, hv.y, a.y);
    a.z = fmaf(g, hv.z, a.z);
    a.w = fmaf(g, hv.w, a.w);
}

// 3 gaussian weights from edge pseudo-coords; muv/ccv constant-indexed -> registers/SGPRs.
static __device__ __forceinline__ float3 gauss3c(float ex, float ey,
                                                 const float* muv, const float* ccv) {
    float3 r;
    float dx, dy;
    dx = ex - muv[0]; dy = ey - muv[1];
    r.x = __expf(fmaf(ccv[0] * dx, dx, ccv[1] * dy * dy));
    dx = ex - muv[2]; dy = ey - muv[3];
    r.y = __expf(fmaf(ccv[2] * dx, dx, ccv[3] * dy * dy));
    dx = ex - muv[4]; dy = ey - muv[5];
    r.z = __expf(fmaf(ccv[4] * dx, dx, ccv[5] * dy * dy));
    return r;
}

// ============ FUSED layer: aggregate (16-B bf16 gather) -> bf16 LDS tile -> MFMA ============
// Batch-2 predicated gather loop (batch-4 spilled under the 64-VGPR budget of
// __launch_bounds__(NT,8)); gaussians computed in-loop (overlap gather latency).
// NT=512 layer 2: LDS 4x33792=135168 <= 160K, 4 blk x 8 waves = 32 waves/CU.
// Tile 64 x KT bf16, odd float4 stride conflict-free. MFMA C/D col=lane&15, row=quad*4+reg.
// FC=true: fused FC 64->2 + log_softmax through LDS (no hC traffic, no extra launch).
template <int CINP, int COUTR, int NT, bool FC>
__global__ __launch_bounds__(NT, 8) void fused_mfma(const unsigned short* __restrict__ h, int hs,
                                                    const float4* __restrict__ ged,
                                                    const int* __restrict__ cursor,
                                                    const int* __restrict__ degi,
                                                    const unsigned short* __restrict__ Wcb,
                                                    const float* __restrict__ bias,
                                                    const float* __restrict__ mu,
                                                    const float* __restrict__ sg,
                                                    unsigned short* __restrict__ out,
                                                    const float* __restrict__ fcw,
                                                    const float* __restrict__ fcb,
                                                    float* __restrict__ fout, int n) {
    constexpr int KT    = 4 * CINP;
    constexpr int ST4   = KT / 8 + 1;            // float4 per LDS row (odd)
    constexpr int ROWU  = ST4 * 8;               // ushorts per LDS row
    constexpr int NSTEP = KT / 32;
    constexpr int NCT   = COUTR / 16;
    constexpr int LPN   = CINP / 8;              // lanes per node
    constexpr int NPP   = NT / LPN;              // nodes per pass
    static_assert(NPP == 64, "single pass over the 64-node tile");
    __shared__ float4 sa[64 * ST4];
    unsigned short* st = (unsigned short*)sa;
    const int row0 = blockIdx.x * 64;

    // ---------------- phase 1: aggregate + own-h into bf16 LDS tile ----------------
    {
        float muv[6], ccv[6];
#pragma unroll
        for (int j = 0; j < 6; ++j) muv[j] = mu[j];
#pragma unroll
        for (int j = 0; j < 6; ++j) {
            float s = sg[j];
            ccv[j] = -0.5f / (1e-15f + s * s);
        }
        const int sub = threadIdx.x / LPN;
        const int li  = threadIdx.x % LPN;       // covers bf16 [li*8, li*8+8)
        int node = row0 + sub; if (node > n - 1) node = n - 1;
        int end = cursor[node];
        int dg  = degi[node];
        int p   = end - dg;
        float4 a[3][2];
#pragma unroll
        for (int k = 0; k < 3; ++k)
#pragma unroll
            for (int q = 0; q < 2; ++q) a[k][q] = make_float4(0, 0, 0, 0);
        for (; p < end; p += 2) {                // predicated batch-2: 2 gathers in flight
            int q1 = (p + 1 < end) ? (p + 1) : p;
            float4 ed0 = ged[p];
            float4 ed1 = ged[q1];
            ushort8v hu0 = *(const ushort8v*)(h + (long)__float_as_int(ed0.x) * hs + li * 8);
            ushort8v hu1 = *(const ushort8v*)(h + (long)__float_as_int(ed1.x) * hs + li * 8);
            float3 g0 = gauss3c(ed0.y, ed0.z, muv, ccv);
            float3 g1 = gauss3c(ed1.y, ed1.z, muv, ccv);
            if (p + 1 >= end) { g1.x = 0.0f; g1.y = 0.0f; g1.z = 0.0f; }
            {
                float4 h0 = make_float4(bf2f(hu0[0]), bf2f(hu0[1]), bf2f(hu0[2]), bf2f(hu0[3]));
                float4 h1 = make_float4(bf2f(hu0[4]), bf2f(hu0[5]), bf2f(hu0[6]), bf2f(hu0[7]));
                fma4(a[0][0], g0.x, h0); fma4(a[0][1], g0.x, h1);
                fma4(a[1][0], g0.y, h0); fma4(a[1][1], g0.y, h1);
                fma4(a[2][0], g0.z, h0); fma4(a[2][1], g0.z, h1);
            }
            {
                float4 h0 = make_float4(bf2f(hu1[0]), bf2f(hu1[1]), bf2f(hu1[2]), bf2f(hu1[3]));
                float4 h1 = make_float4(bf2f(hu1[4]), bf2f(hu1[5]), bf2f(hu1[6]), bf2f(hu1[7]));
                fma4(a[0][0], g1.x, h0); fma4(a[0][1], g1.x, h1);
                fma4(a[1][0], g1.y, h0); fma4(a[1][1], g1.y, h1);
                fma4(a[2][0], g1.z, h0); fma4(a[2][1], g1.z, h1);
            }
        }
        float inv = 1.0f / (float)max(dg, 1);
#pragma unroll
        for (int k = 0; k < 3; ++k)
#pragma unroll
            for (int q = 0; q < 2; ++q) fma4(a[k][q], inv - 1.0f, a[k][q]);  // *= inv
        ushort8v hv8 = *(const ushort8v*)(h + (long)node * hs + li * 8);     // raw bf16
        int base = sub * ROWU;
        int c8b  = li * 8;
#pragma unroll
        for (int k = 0; k < 3; ++k) {
            ushort8v v;
            v[0] = bf16rne(a[k][0].x); v[1] = bf16rne(a[k][0].y);
            v[2] = bf16rne(a[k][0].z); v[3] = bf16rne(a[k][0].w);
            v[4] = bf16rne(a[k][1].x); v[5] = bf16rne(a[k][1].y);
            v[6] = bf16rne(a[k][1].z); v[7] = bf16rne(a[k][1].w);
            *(ushort8v*)(st + base + k * CINP + c8b) = v;
        }
        *(ushort8v*)(st + base + 3 * CINP + c8b) = hv8;
    }
    __syncthreads();

    // ---------------- phase 2: MFMA GEMM from LDS tile ----------------
    constexpr int NW    = NT / 64;               // waves per block
    constexpr int TILES = 4 * NCT;               // 4 row-groups x NCT col-tiles
    constexpr int TPW   = TILES / NW;
    constexpr int RST   = NW / NCT;              // row-group stride per wave
    static_assert(NW % NCT == 0 && TILES % NW == 0, "tile remap");
    const int lane = threadIdx.x & 63;
    const int wv   = threadIdx.x >> 6;
    const int quad = lane >> 4;
    const int c16  = lane & 15;
    const int ct   = wv % NCT;                   // fixed column-tile per wave
    const int rg0  = wv / NCT;
    f32x4 acc[TPW];
#pragma unroll
    for (int i = 0; i < TPW; ++i) acc[i] = (f32x4){0.0f, 0.0f, 0.0f, 0.0f};
    const unsigned short* bcol = Wcb + (ct * 16 + c16) * KT;
#pragma unroll
    for (int s = 0; s < NSTEP; ++s) {
        short8 bf = *(const short8*)(bcol + s * 32 + quad * 8);  // hoisted: same ct all tiles
#pragma unroll
        for (int i = 0; i < TPW; ++i) {
            const unsigned short* arow = st + (16 * (rg0 + i * RST) + c16) * ROWU;
            short8 af = *(const short8*)(arow + s * 32 + quad * 8);
            acc[i] = __builtin_amdgcn_mfma_f32_16x16x32_bf16(af, bf, acc[i], 0, 0, 0);
        }
    }
    if constexpr (!FC) {
        // epilogue: C/D col=lane&15, row=quad*4+reg; write bf16
#pragma unroll
        for (int i = 0; i < TPW; ++i) {
            int rg  = rg0 + i * RST;
            int col = ct * 16 + c16;
            float b = bias[col];
#pragma unroll
            for (int r = 0; r < 4; ++r) {
                int grow = row0 + rg * 16 + quad * 4 + r;
                if (grow < n)
                    out[(long)grow * COUTR + col] = bf16rne(fmaxf(acc[i][r] + b, 0.0f));
            }
        }
    } else {
        // fused FC(64->2)+log_softmax: relu'd bf16 row -> LDS (reuse sa) -> per-node dot
        static_assert(COUTR == 64, "FC fusion assumes 64-wide rows");
        constexpr int FS = 72;                   // ushort stride, 144 B rows (16-B aligned)
        __syncthreads();                         // all MFMA LDS reads complete
        {
            int col = ct * 16 + c16;
            float b = bias[col];
#pragma unroll
            for (int i = 0; i < TPW; ++i) {
                int rg = rg0 + i * RST;
#pragma unroll
                for (int r = 0; r < 4; ++r) {
                    int lr2 = rg * 16 + quad * 4 + r;
                    st[lr2 * FS + col] = bf16rne(fmaxf(acc[i][r] + b, 0.0f));
                }
            }
        }
        __syncthreads();
        int t = threadIdx.x;
        if (t < 64) {
            int node = row0 + t;
            if (node < n) {
                const ushort8v* hr = (const ushort8v*)(st + t * FS);
                float l0 = fcb[0];
                float l1 = fcb[1];
#pragma unroll
                for (int j8 = 0; j8 < 8; ++j8) {
                    ushort8v hv = hr[j8];
#pragma unroll
                    for (int j = 0; j < 8; ++j) {
                        float hvf = bf2f(hv[j]);
                        l0 = fmaf(hvf, fcw[2 * (8 * j8 + j)], l0);
                        l1 = fmaf(hvf, fcw[2 * (8 * j8 + j) + 1], l1);
                    }
                }
                float mx  = fmaxf(l0, l1);
                float lse = mx + logf(__expf(l0 - mx) + __expf(l1 - mx));
                fout[2 * (long)node]     = l0 - lse;
                fout[2 * (long)node + 1] = l1 - lse;
            }
        }
    }
}

extern "C" void kernel_launch(void* const* d_in, const int* in_sizes, int n_in,
                              void* d_out, int out_size, void* d_ws, size_t ws_size,
                              hipStream_t stream) {
    const float* x   = (const float*)d_in[0];
    const int*   ei  = (const int*)d_in[1];
    const float* ea  = (const float*)d_in[2];
    const float* g_[3]  = {(const float*)d_in[3],  (const float*)d_in[8],  (const float*)d_in[13]};
    const float* mu_[3] = {(const float*)d_in[4],  (const float*)d_in[9],  (const float*)d_in[14]};
    const float* sg_[3] = {(const float*)d_in[5],  (const float*)d_in[10], (const float*)d_in[15]};
    const float* rt_[3] = {(const float*)d_in[6],  (const float*)d_in[11], (const float*)d_in[16]};
    const float* bs_[3] = {(const float*)d_in[7],  (const float*)d_in[12], (const float*)d_in[17]};
    const float* fcw = (const float*)d_in[18];
    const float* fcb = (const float*)d_in[19];
    float* out = (float*)d_out;
    (void)in_sizes; (void)n_in; (void)out_size; (void)ws_size;

    // workspace carve-up (~35 MB)
    char* w = (char*)d_ws;
    size_t off = 0;
    auto carve = [&](size_t bytes) -> void* {
        void* p = (void*)(w + off);
        off += (bytes + 255) & ~(size_t)255;
        return p;
    };
    int*    degi   = (int*)carve((size_t)NN * 4);
    int*    cursor = (int*)carve((size_t)NN * 4);
    int*    eidx   = (int*)carve((size_t)NE * 4);       // CSR-ordered edge ids (4 B scatter)
    float4* gedr   = (float4*)carve((size_t)NE * 16);   // {src, ex, ey, _} CSR-ordered
    int*    bsum   = (int*)carve(1024 * 4);
    unsigned short* W0 = (unsigned short*)carve((size_t)32 * 128 * 2);
    unsigned short* W1 = (unsigned short*)carve((size_t)64 * 128 * 2);
    unsigned short* W2 = (unsigned short*)carve((size_t)64 * 256 * 2);
    unsigned short* xp = (unsigned short*)carve((size_t)NN * 32 * 2);  // bf16 [N,32]
    unsigned short* hA = (unsigned short*)carve((size_t)NN * 32 * 2);  // bf16 [N,32]
    unsigned short* hB = (unsigned short*)carve((size_t)NN * 64 * 2);  // bf16 [N,64]

    const int* src = ei;
    const int* dst = ei + NE;
    const int EB = (NE + 255) / 256;
    const int PB = (NN + 255) / 256;
    const int WB = 112;               // (32*128 + 64*128 + 64*256) / 256
    const int GB = (NN + 63) / 64;    // 2561 blocks: 64 nodes per block

    // ---- CSR build (4-B scatter) + record/pad/Wcb build (one launch) ----
    hipMemsetAsync(degi, 0, (size_t)NN * 4, stream);
    deg_count<<<EB, 256, 0, stream>>>(dst, degi, NE);
    scan1<<<NB, 256, 0, stream>>>(degi, cursor, bsum, NN);
    scan2<<<1, 1024, 0, stream>>>(bsum, NB);
    scan3<<<NB, 256, 0, stream>>>(cursor, bsum, NN);
    scatter_idx<<<(NE + 511) / 512, 256, 0, stream>>>(dst, cursor, eidx, NE);
    gather_build<<<EB + PB + WB, 256, 0, stream>>>(eidx, src, ea, gedr, x, xp,
                                                   g_[0], rt_[0], g_[1], rt_[1], g_[2], rt_[2],
                                                   W0, W1, W2, NE, EB, PB, NN);

    // ---- layer 0: 22(pad32) -> 32 ----
    fused_mfma<32, 32, 256, false><<<GB, 256, 0, stream>>>(xp, 32, gedr, cursor, degi,
                                                           W0, bs_[0], mu_[0], sg_[0],
                                                           hA, nullptr, nullptr,
                                                           nullptr, NN);
    // ---- layer 1: 32 -> 64 ----
    fused_mfma<32, 64, 256, false><<<GB, 256, 0, stream>>>(hA, 32, gedr, cursor, degi,
                                                           W1, bs_[1], mu_[1], sg_[1],
                                                           hB, nullptr, nullptr,
                                                           nullptr, NN);
    // ---- layer 2: 64 -> 64, 512 threads (32 waves/CU), fused FC + log_softmax ----
    fused_mfma<64, 64, 512, true><<<GB, 512, 0, stream>>>(hB, 64, gedr, cursor, degi,
                                                          W2, bs_[2], mu_[2], sg_[2],
                                                          nullptr, fcw, fcb,
                                                          out, NN);
}

// Round 4
// 322.411 us; speedup vs baseline: 1.1202x; 1.1202x over previous
//
#include <hip/hip_runtime.h>

#define NN 163842
#define NE 983040
#define NB 641   // ceil(NN/256)
#define BC 32    // bucket capacity: Poisson(6) max over 164k nodes ~22; 32 = safe

using short8   = __attribute__((ext_vector_type(8))) short;
using ushort8v = __attribute__((ext_vector_type(8))) unsigned short;
using f32x4    = __attribute__((ext_vector_type(4))) float;

// ---- bucketed CSR scatter: ONE atomic pass (deg_count eliminated) ----
// p = atomicAdd(cnt[dst]); eidx[dst*BC+p] = e. cnt doubles as the degree array.
// 2 edges/thread = 2 independent atomic chains in flight per lane.
__global__ __launch_bounds__(256) void scatter_bucket(const int* __restrict__ dst,
                                                      int* __restrict__ cnt,
                                                      int* __restrict__ eidx, int E) {
    int e0 = blockIdx.x * 512 + threadIdx.x;
    int e1 = e0 + 256;
    int d0 = (e0 < E) ? dst[e0] : 0;
    int d1 = (e1 < E) ? dst[e1] : 0;
    int p0 = 0, p1 = 0;
    if (e0 < E) p0 = atomicAdd(&cnt[d0], 1);
    if (e1 < E) p1 = atomicAdd(&cnt[d1], 1);
    if (e0 < E && p0 < BC) eidx[d0 * BC + p0] = e0;
    if (e1 < E && p1 < BC) eidx[d1 * BC + p1] = e1;
}

// ---------------- exclusive scan of clamped cnt -> cursor (start offsets) ----------------
__global__ __launch_bounds__(256) void scan1(const int* __restrict__ degi,
                                             int* __restrict__ cursor,
                                             int* __restrict__ bsum, int n) {
    __shared__ int tmp[256];
    int t = threadIdx.x;
    int i = blockIdx.x * 256 + t;
    int v = (i < n) ? min(degi[i], BC) : 0;
    tmp[t] = v;
    __syncthreads();
    for (int o = 1; o < 256; o <<= 1) {
        int x = (t >= o) ? tmp[t - o] : 0;
        __syncthreads();
        tmp[t] += x;
        __syncthreads();
    }
    if (i < n) cursor[i] = tmp[t] - v;            // exclusive (start)
    if (t == 255) bsum[blockIdx.x] = tmp[255];    // block total
}

__global__ void scan2(int* __restrict__ bsum, int nb) {
    __shared__ int tmp[1024];
    int t = threadIdx.x;
    int v = (t < nb) ? bsum[t] : 0;
    tmp[t] = v;
    __syncthreads();
    for (int o = 1; o < 1024; o <<= 1) {
        int x = (t >= o) ? tmp[t - o] : 0;
        __syncthreads();
        tmp[t] += x;
        __syncthreads();
    }
    if (t < nb) bsum[t] = tmp[t] - v;
}

__global__ __launch_bounds__(256) void scan3(int* __restrict__ cursor,
                                             const int* __restrict__ bsum, int n) {
    int i = blockIdx.x * 256 + threadIdx.x;
    if (i < n) cursor[i] += bsum[blockIdx.x];
}

static __device__ __forceinline__ unsigned short bf16rne(float x) {
    unsigned u = __float_as_uint(x);
    u += 0x7FFFu + ((u >> 16) & 1u);      // round-to-nearest-even
    return (unsigned short)(u >> 16);
}

static __device__ __forceinline__ float bf2f(unsigned short u) {
    return __uint_as_float(((unsigned)u) << 16);
}

// ---- transposed bf16 weights Wcb[n][k], k-major ----
template <int CIN, int CINP, int COUTR>
static __device__ __forceinline__ void wcb_emit(int t, const float* __restrict__ g,
                                                const float* __restrict__ root,
                                                unsigned short* __restrict__ Wcb) {
    constexpr int KTl = 4 * CINP;
    int nIdx = t / KTl, k = t - nIdx * KTl;
    int seg = k / CINP, c = k - seg * CINP;
    float v = 0.0f;
    if (c < CIN)
        v = (seg < 3) ? g[c * (3 * COUTR) + seg * COUTR + nIdx] : root[c * COUTR + nIdx];
    Wcb[t] = bf16rne(v);
}

// ---- ONE launch: bucket->CSR compaction (streaming gedr write) + x pad + Wcb ----
// Compaction: 8 lanes/node; eidx bucket reads coalesced; src[e] 4 B + ea[e] 8 B random
// gathers (L2/L3-resident); gedr[start+c] coalesced 16-B store.
__global__ __launch_bounds__(256) void gather_build(const int* __restrict__ eidx,
                                                    const int* __restrict__ cnt,
                                                    const int* __restrict__ cursor,
                                                    const int* __restrict__ src,
                                                    const float* __restrict__ ea,
                                                    float4* __restrict__ gedr,
                                                    const float* __restrict__ x,
                                                    unsigned short* __restrict__ xp,
                                                    const float* __restrict__ g0, const float* __restrict__ rt0,
                                                    const float* __restrict__ g1, const float* __restrict__ rt1,
                                                    const float* __restrict__ g2, const float* __restrict__ rt2,
                                                    unsigned short* __restrict__ W0,
                                                    unsigned short* __restrict__ W1,
                                                    unsigned short* __restrict__ W2,
                                                    int CBLK, int PBLK, int n) {
    int bid = blockIdx.x;
    if (bid < CBLK) {
        int node = bid * 32 + (threadIdx.x >> 3);
        int li   = threadIdx.x & 7;
        if (node >= n) return;
        int dgc = min(cnt[node], BC);
        int st  = cursor[node];
        for (int c = li; c < dgc; c += 8) {
            int e = eidx[node * BC + c];
            float2 exy = *(const float2*)(ea + 2 * (size_t)e);
            gedr[st + c] = make_float4(__int_as_float(src[e]), exy.x, exy.y, 0.0f);
        }
        return;
    }
    bid -= CBLK;
    if (bid < PBLK) {
        // ---- pad path: one thread per node, float2 loads + ushort8 stores ----
        int r = bid * 256 + threadIdx.x;
        if (r >= n) return;
        float v[22];
        const float2* x2 = (const float2*)(x + (size_t)r * 22);  // 88 B row, 8-aligned
#pragma unroll
        for (int j = 0; j < 11; ++j) *(float2*)(v + 2 * j) = x2[j];
        unsigned short* op = xp + (size_t)r * 32;
#pragma unroll
        for (int g8 = 0; g8 < 4; ++g8) {
            ushort8v o;
#pragma unroll
            for (int j = 0; j < 8; ++j) {
                int c = g8 * 8 + j;
                o[j] = (c < 22) ? bf16rne(v[c]) : (unsigned short)0;
            }
            *(ushort8v*)(op + g8 * 8) = o;
        }
        return;
    }
    bid -= PBLK;
    int t = bid * 256 + threadIdx.x;
    constexpr int T0 = 32 * 128, T1 = 64 * 128, T2 = 64 * 256;
    if (t < T0)                wcb_emit<22, 32, 32>(t, g0, rt0, W0);
    else if (t < T0 + T1)      wcb_emit<32, 32, 64>(t - T0, g1, rt1, W1);
    else if (t < T0 + T1 + T2) wcb_emit<64, 64, 64>(t - T0 - T1, g2, rt2, W2);
}

static __device__ __forceinline__ void fma4(float4& a, float g, const float4& hv) {
    a.x = fmaf(g, hv.x, a.x);
    a.y = fmaf(g, hv.y, a.y);
    a.z = fmaf(g, hv.z, a.z);
    a.w = fmaf(g, hv.w, a.w);
}

// 3 gaussian weights from edge pseudo-coords; muv/ccv constant-indexed -> registers/SGPRs.
static __device__ __forceinline__ float3 gauss3c(float ex, float ey,
                                                 const float* muv, const float* ccv) {
    float3 r;
    float dx, dy;
    dx = ex - muv[0]; dy = ey - muv[1];
    r.x = __expf(fmaf(ccv[0] * dx, dx, ccv[1] * dy * dy));
    dx = ex - muv[2]; dy = ey - muv[3];
    r.y = __expf(fmaf(ccv[2] * dx, dx, ccv[3] * dy * dy));
    dx = ex - muv[4]; dy = ey - muv[5];
    r.z = __expf(fmaf(ccv[4] * dx, dx, ccv[5] * dy * dy));
    return r;
}

// ============ FUSED layer: aggregate (16-B bf16 gather) -> bf16 LDS tile -> MFMA ============
// Batch-2 predicated gather loop (batch-4 spilled under the 64-VGPR budget of
// __launch_bounds__(NT,8)); gaussians computed in-loop (overlap gather latency).
// cursor = CSR START offsets (bucketed build); end = start + clamped degree.
// NT=512 layer 2: LDS 4x33792=135168 <= 160K, 4 blk x 8 waves = 32 waves/CU.
// Tile 64 x KT bf16, odd float4 stride conflict-free. MFMA C/D col=lane&15, row=quad*4+reg.
// FC=true: fused FC 64->2 + log_softmax through LDS (no hC traffic, no extra launch).
template <int CINP, int COUTR, int NT, bool FC>
__global__ __launch_bounds__(NT, 8) void fused_mfma(const unsigned short* __restrict__ h, int hs,
                                                    const float4* __restrict__ ged,
                                                    const int* __restrict__ cursor,
                                                    const int* __restrict__ degi,
                                                    const unsigned short* __restrict__ Wcb,
                                                    const float* __restrict__ bias,
                                                    const float* __restrict__ mu,
                                                    const float* __restrict__ sg,
                                                    unsigned short* __restrict__ out,
                                                    const float* __restrict__ fcw,
                                                    const float* __restrict__ fcb,
                                                    float* __restrict__ fout, int n) {
    constexpr int KT    = 4 * CINP;
    constexpr int ST4   = KT / 8 + 1;            // float4 per LDS row (odd)
    constexpr int ROWU  = ST4 * 8;               // ushorts per LDS row
    constexpr int NSTEP = KT / 32;
    constexpr int NCT   = COUTR / 16;
    constexpr int LPN   = CINP / 8;              // lanes per node
    constexpr int NPP   = NT / LPN;              // nodes per pass
    static_assert(NPP == 64, "single pass over the 64-node tile");
    __shared__ float4 sa[64 * ST4];
    unsigned short* st = (unsigned short*)sa;
    const int row0 = blockIdx.x * 64;

    // ---------------- phase 1: aggregate + own-h into bf16 LDS tile ----------------
    {
        float muv[6], ccv[6];
#pragma unroll
        for (int j = 0; j < 6; ++j) muv[j] = mu[j];
#pragma unroll
        for (int j = 0; j < 6; ++j) {
            float s = sg[j];
            ccv[j] = -0.5f / (1e-15f + s * s);
        }
        const int sub = threadIdx.x / LPN;
        const int li  = threadIdx.x % LPN;       // covers bf16 [li*8, li*8+8)
        int node = row0 + sub; if (node > n - 1) node = n - 1;
        int p   = cursor[node];                  // start
        int dg  = min(degi[node], BC);
        int end = p + dg;
        float4 a[3][2];
#pragma unroll
        for (int k = 0; k < 3; ++k)
#pragma unroll
            for (int q = 0; q < 2; ++q) a[k][q] = make_float4(0, 0, 0, 0);
        for (; p < end; p += 2) {                // predicated batch-2: 2 gathers in flight
            int q1 = (p + 1 < end) ? (p + 1) : p;
            float4 ed0 = ged[p];
            float4 ed1 = ged[q1];
            ushort8v hu0 = *(const ushort8v*)(h + (long)__float_as_int(ed0.x) * hs + li * 8);
            ushort8v hu1 = *(const ushort8v*)(h + (long)__float_as_int(ed1.x) * hs + li * 8);
            float3 g0 = gauss3c(ed0.y, ed0.z, muv, ccv);
            float3 g1 = gauss3c(ed1.y, ed1.z, muv, ccv);
            if (p + 1 >= end) { g1.x = 0.0f; g1.y = 0.0f; g1.z = 0.0f; }
            {
                float4 h0 = make_float4(bf2f(hu0[0]), bf2f(hu0[1]), bf2f(hu0[2]), bf2f(hu0[3]));
                float4 h1 = make_float4(bf2f(hu0[4]), bf2f(hu0[5]), bf2f(hu0[6]), bf2f(hu0[7]));
                fma4(a[0][0], g0.x, h0); fma4(a[0][1], g0.x, h1);
                fma4(a[1][0], g0.y, h0); fma4(a[1][1], g0.y, h1);
                fma4(a[2][0], g0.z, h0); fma4(a[2][1], g0.z, h1);
            }
            {
                float4 h0 = make_float4(bf2f(hu1[0]), bf2f(hu1[1]), bf2f(hu1[2]), bf2f(hu1[3]));
                float4 h1 = make_float4(bf2f(hu1[4]), bf2f(hu1[5]), bf2f(hu1[6]), bf2f(hu1[7]));
                fma4(a[0][0], g1.x, h0); fma4(a[0][1], g1.x, h1);
                fma4(a[1][0], g1.y, h0); fma4(a[1][1], g1.y, h1);
                fma4(a[2][0], g1.z, h0); fma4(a[2][1], g1.z, h1);
            }
        }
        float inv = 1.0f / (float)max(dg, 1);
#pragma unroll
        for (int k = 0; k < 3; ++k)
#pragma unroll
            for (int q = 0; q < 2; ++q) fma4(a[k][q], inv - 1.0f, a[k][q]);  // *= inv
        ushort8v hv8 = *(const ushort8v*)(h + (long)node * hs + li * 8);     // raw bf16
        int base = sub * ROWU;
        int c8b  = li * 8;
#pragma unroll
        for (int k = 0; k < 3; ++k) {
            ushort8v v;
            v[0] = bf16rne(a[k][0].x); v[1] = bf16rne(a[k][0].y);
            v[2] = bf16rne(a[k][0].z); v[3] = bf16rne(a[k][0].w);
            v[4] = bf16rne(a[k][1].x); v[5] = bf16rne(a[k][1].y);
            v[6] = bf16rne(a[k][1].z); v[7] = bf16rne(a[k][1].w);
            *(ushort8v*)(st + base + k * CINP + c8b) = v;
        }
        *(ushort8v*)(st + base + 3 * CINP + c8b) = hv8;
    }
    __syncthreads();

    // ---------------- phase 2: MFMA GEMM from LDS tile ----------------
    constexpr int NW    = NT / 64;               // waves per block
    constexpr int TILES = 4 * NCT;               // 4 row-groups x NCT col-tiles
    constexpr int TPW   = TILES / NW;
    constexpr int RST   = NW / NCT;              // row-group stride per wave
    static_assert(NW % NCT == 0 && TILES % NW == 0, "tile remap");
    const int lane = threadIdx.x & 63;
    const int wv   = threadIdx.x >> 6;
    const int quad = lane >> 4;
    const int c16  = lane & 15;
    const int ct   = wv % NCT;                   // fixed column-tile per wave
    const int rg0  = wv / NCT;
    f32x4 acc[TPW];
#pragma unroll
    for (int i = 0; i < TPW; ++i) acc[i] = (f32x4){0.0f, 0.0f, 0.0f, 0.0f};
    const unsigned short* bcol = Wcb + (ct * 16 + c16) * KT;
#pragma unroll
    for (int s = 0; s < NSTEP; ++s) {
        short8 bf = *(const short8*)(bcol + s * 32 + quad * 8);  // hoisted: same ct all tiles
#pragma unroll
        for (int i = 0; i < TPW; ++i) {
            const unsigned short* arow = st + (16 * (rg0 + i * RST) + c16) * ROWU;
            short8 af = *(const short8*)(arow + s * 32 + quad * 8);
            acc[i] = __builtin_amdgcn_mfma_f32_16x16x32_bf16(af, bf, acc[i], 0, 0, 0);
        }
    }
    if constexpr (!FC) {
        // epilogue: C/D col=lane&15, row=quad*4+reg; write bf16
#pragma unroll
        for (int i = 0; i < TPW; ++i) {
            int rg  = rg0 + i * RST;
            int col = ct * 16 + c16;
            float b = bias[col];
#pragma unroll
            for (int r = 0; r < 4; ++r) {
                int grow = row0 + rg * 16 + quad * 4 + r;
                if (grow < n)
                    out[(long)grow * COUTR + col] = bf16rne(fmaxf(acc[i][r] + b, 0.0f));
            }
        }
    } else {
        // fused FC(64->2)+log_softmax: relu'd bf16 row -> LDS (reuse sa) -> per-node dot
        static_assert(COUTR == 64, "FC fusion assumes 64-wide rows");
        constexpr int FS = 72;                   // ushort stride, 144 B rows (16-B aligned)
        __syncthreads();                         // all MFMA LDS reads complete
        {
            int col = ct * 16 + c16;
            float b = bias[col];
#pragma unroll
            for (int i = 0; i < TPW; ++i) {
                int rg = rg0 + i * RST;
#pragma unroll
                for (int r = 0; r < 4; ++r) {
                    int lr2 = rg * 16 + quad * 4 + r;
                    st[lr2 * FS + col] = bf16rne(fmaxf(acc[i][r] + b, 0.0f));
                }
            }
        }
        __syncthreads();
        int t = threadIdx.x;
        if (t < 64) {
            int node = row0 + t;
            if (node < n) {
                const ushort8v* hr = (const ushort8v*)(st + t * FS);
                float l0 = fcb[0];
                float l1 = fcb[1];
#pragma unroll
                for (int j8 = 0; j8 < 8; ++j8) {
                    ushort8v hv = hr[j8];
#pragma unroll
                    for (int j = 0; j < 8; ++j) {
                        float hvf = bf2f(hv[j]);
                        l0 = fmaf(hvf, fcw[2 * (8 * j8 + j)], l0);
                        l1 = fmaf(hvf, fcw[2 * (8 * j8 + j) + 1], l1);
                    }
                }
                float mx  = fmaxf(l0, l1);
                float lse = mx + logf(__expf(l0 - mx) + __expf(l1 - mx));
                fout[2 * (long)node]     = l0 - lse;
                fout[2 * (long)node + 1] = l1 - lse;
            }
        }
    }
}

extern "C" void kernel_launch(void* const* d_in, const int* in_sizes, int n_in,
                              void* d_out, int out_size, void* d_ws, size_t ws_size,
                              hipStream_t stream) {
    const float* x   = (const float*)d_in[0];
    const int*   ei  = (const int*)d_in[1];
    const float* ea  = (const float*)d_in[2];
    const float* g_[3]  = {(const float*)d_in[3],  (const float*)d_in[8],  (const float*)d_in[13]};
    const float* mu_[3] = {(const float*)d_in[4],  (const float*)d_in[9],  (const float*)d_in[14]};
    const float* sg_[3] = {(const float*)d_in[5],  (const float*)d_in[10], (const float*)d_in[15]};
    const float* rt_[3] = {(const float*)d_in[6],  (const float*)d_in[11], (const float*)d_in[16]};
    const float* bs_[3] = {(const float*)d_in[7],  (const float*)d_in[12], (const float*)d_in[17]};
    const float* fcw = (const float*)d_in[18];
    const float* fcb = (const float*)d_in[19];
    float* out = (float*)d_out;
    (void)in_sizes; (void)n_in; (void)out_size; (void)ws_size;

    // workspace carve-up (~70 MB)
    char* w = (char*)d_ws;
    size_t off = 0;
    auto carve = [&](size_t bytes) -> void* {
        void* p = (void*)(w + off);
        off += (bytes + 255) & ~(size_t)255;
        return p;
    };
    int*    cnt    = (int*)carve((size_t)NN * 4);        // degree (bucket fill count)
    int*    cursor = (int*)carve((size_t)NN * 4);        // CSR start offsets
    int*    eidx   = (int*)carve((size_t)NN * BC * 4);   // padded buckets (21 MB)
    float4* gedr   = (float4*)carve((size_t)NE * 16);    // {src, ex, ey, _} CSR-ordered
    int*    bsum   = (int*)carve(1024 * 4);
    unsigned short* W0 = (unsigned short*)carve((size_t)32 * 128 * 2);
    unsigned short* W1 = (unsigned short*)carve((size_t)64 * 128 * 2);
    unsigned short* W2 = (unsigned short*)carve((size_t)64 * 256 * 2);
    unsigned short* xp = (unsigned short*)carve((size_t)NN * 32 * 2);  // bf16 [N,32]
    unsigned short* hA = (unsigned short*)carve((size_t)NN * 32 * 2);  // bf16 [N,32]
    unsigned short* hB = (unsigned short*)carve((size_t)NN * 64 * 2);  // bf16 [N,64]

    const int* src = ei;
    const int* dst = ei + NE;
    const int CB = (NN + 31) / 32;    // compaction blocks (32 nodes/block, 8 lanes/node)
    const int PB = (NN + 255) / 256;  // pad blocks
    const int WB = 112;               // (32*128 + 64*128 + 64*256) / 256
    const int GB = (NN + 63) / 64;    // 2561 blocks: 64 nodes per block

    // ---- bucketed CSR build: ONE atomic pass + scan + compaction ----
    hipMemsetAsync(cnt, 0, (size_t)NN * 4, stream);
    scatter_bucket<<<(NE + 511) / 512, 256, 0, stream>>>(dst, cnt, eidx, NE);
    scan1<<<NB, 256, 0, stream>>>(cnt, cursor, bsum, NN);
    scan2<<<1, 1024, 0, stream>>>(bsum, NB);
    scan3<<<NB, 256, 0, stream>>>(cursor, bsum, NN);
    gather_build<<<CB + PB + WB, 256, 0, stream>>>(eidx, cnt, cursor, src, ea, gedr, x, xp,
                                                   g_[0], rt_[0], g_[1], rt_[1], g_[2], rt_[2],
                                                   W0, W1, W2, CB, PB, NN);

    // ---- layer 0: 22(pad32) -> 32 ----
    fused_mfma<32, 32, 256, false><<<GB, 256, 0, stream>>>(xp, 32, gedr, cursor, cnt,
                                                           W0, bs_[0], mu_[0], sg_[0],
                                                           hA, nullptr, nullptr,
                                                           nullptr, NN);
    // ---- layer 1: 32 -> 64 ----
    fused_mfma<32, 64, 256, false><<<GB, 256, 0, stream>>>(hA, 32, gedr, cursor, cnt,
                                                           W1, bs_[1], mu_[1], sg_[1],
                                                           hB, nullptr, nullptr,
                                                           nullptr, NN);
    // ---- layer 2: 64 -> 64, 512 threads (32 waves/CU), fused FC + log_softmax ----
    fused_mfma<64, 64, 512, true><<<GB, 512, 0, stream>>>(hB, 64, gedr, cursor, cnt,
                                                          W2, bs_[2], mu_[2], sg_[2],
                                                          nullptr, fcw, fcb,
                                                          out, NN);
}